// Round 3
// baseline (519.541 us; speedup 1.0000x reference)
//
#include <hip/hip_runtime.h>
#include <hip/hip_bf16.h>

#define SLOPE 0.2f

// ---------- small utils ----------

__global__ __launch_bounds__(256) void k_zero(int* __restrict__ p, int n) {
    int i = blockIdx.x * 256 + threadIdx.x;
    if (i < n) p[i] = 0;
}

// detect int64 vs int32 edge_index: odd int32 words are (nearly) all 0 iff int64
__global__ __launch_bounds__(256) void k_detect(const int* __restrict__ ei, int nwords,
                                                int* __restrict__ flag) {
    __shared__ int cnt;
    if (threadIdx.x == 0) cnt = 0;
    __syncthreads();
    int z = 0;
    for (int i = threadIdx.x; i < nwords; i += 256)
        if ((i & 1) && ei[i] == 0) z++;
    atomicAdd(&cnt, z);
    __syncthreads();
    if (threadIdx.x == 0) *flag = (cnt > nwords / 4) ? 1 : 0;
}

__device__ inline int esrc_at(const int* ei, int E, int f, int e) {
    return f ? ei[2 * e] : ei[e];
}
__device__ inline int edst_at(const int* ei, int E, int f, int e) {
    return f ? ei[2 * (E + e)] : ei[E + e];
}

// ---------- CSR build ----------

__global__ __launch_bounds__(256) void k_hist(const int* __restrict__ ei, int E,
                                              const int* __restrict__ flag,
                                              int* __restrict__ deg) {
    int e = blockIdx.x * 256 + threadIdx.x;
    if (e < E) atomicAdd(&deg[edst_at(ei, E, *flag, e)], 1);
}

__global__ __launch_bounds__(256) void k_scan_part(const int* __restrict__ deg, int n,
                                                   int* __restrict__ parts) {
    __shared__ int s[256];
    int base = blockIdx.x * 1024;
    int sum = 0;
    for (int j = threadIdx.x; j < 1024; j += 256) {
        int i = base + j;
        sum += (i < n) ? deg[i] : 0;
    }
    s[threadIdx.x] = sum;
    __syncthreads();
    for (int off = 128; off > 0; off >>= 1) {
        if (threadIdx.x < off) s[threadIdx.x] += s[threadIdx.x + off];
        __syncthreads();
    }
    if (threadIdx.x == 0) parts[blockIdx.x] = s[0];
}

__global__ __launch_bounds__(64) void k_scan_top(int* __restrict__ parts, int NB,
                                                 int* __restrict__ rowp, int n) {
    if (threadIdx.x == 0 && blockIdx.x == 0) {
        int run = 0;
        for (int b = 0; b < NB; ++b) {
            int t = parts[b];
            parts[b] = run;
            run += t;
        }
        rowp[n] = run;
    }
}

__global__ __launch_bounds__(256) void k_scan_final(const int* __restrict__ deg, int n,
                                                    const int* __restrict__ parts,
                                                    int* __restrict__ rowp) {
    __shared__ int s[256];
    int t = threadIdx.x;
    int base = blockIdx.x * 1024 + t * 4;
    int v0 = (base + 0 < n) ? deg[base + 0] : 0;
    int v1 = (base + 1 < n) ? deg[base + 1] : 0;
    int v2 = (base + 2 < n) ? deg[base + 2] : 0;
    int v3 = (base + 3 < n) ? deg[base + 3] : 0;
    int mysum = v0 + v1 + v2 + v3;
    s[t] = mysum;
    __syncthreads();
    for (int off = 1; off < 256; off <<= 1) {
        int add = (t >= off) ? s[t - off] : 0;
        __syncthreads();
        s[t] += add;
        __syncthreads();
    }
    int excl = parts[blockIdx.x] + s[t] - mysum;
    if (base + 0 < n) rowp[base + 0] = excl;
    if (base + 1 < n) rowp[base + 1] = excl + v0;
    if (base + 2 < n) rowp[base + 2] = excl + v0 + v1;
    if (base + 3 < n) rowp[base + 3] = excl + v0 + v1 + v2;
}

__global__ __launch_bounds__(256) void k_scatter(const int* __restrict__ ei, int E,
                                                 const int* __restrict__ flag,
                                                 const int* __restrict__ rowp,
                                                 int* __restrict__ cur,
                                                 int* __restrict__ ssrc) {
    int e = blockIdx.x * 256 + threadIdx.x;
    if (e < E) {
        int f = *flag;
        int i = edst_at(ei, E, f, e);
        int pos = rowp[i] + atomicAdd(&cur[i], 1);
        ssrc[pos] = esrc_at(ei, E, f, e);
    }
}

// ---------- dtype helpers ----------

__device__ inline float loadf(const float* p, size_t i) { return p[i]; }
__device__ inline float loadf(const __hip_bfloat16* p, size_t i) {
    return __bfloat162float(p[i]);
}
__device__ inline void storef(float* p, size_t i, float v) { p[i] = v; }
__device__ inline void storef(__hip_bfloat16* p, size_t i, float v) {
    p[i] = __float2bfloat16(v);
}

// ---------- per-layer kernels ----------

// xl = x@Wl + bl ; xr = x@Wr + br   (D = 64), W staged in LDS
template <typename ST>
__global__ __launch_bounds__(256) void k_lin2(const float* __restrict__ x,
                                              const float* __restrict__ Wl,
                                              const float* __restrict__ bl,
                                              const float* __restrict__ Wr,
                                              const float* __restrict__ br,
                                              ST* __restrict__ xl,
                                              ST* __restrict__ xr, int n) {
    __shared__ float sWl[4096], sWr[4096], sbl[64], sbr[64];
    int t = threadIdx.x;
    for (int k = t; k < 4096; k += 256) {
        sWl[k] = Wl[k];
        sWr[k] = Wr[k];
    }
    if (t < 64) {
        sbl[t] = bl[t];
        sbr[t] = br[t];
    }
    __syncthreads();
    int col = t & 63;
    int rl = t >> 6;
    int ngroups = (n + 3) >> 2;
    for (int g = blockIdx.x; g < ngroups; g += gridDim.x) {
        int row = g * 4 + rl;
        if (row < n) {
            const float* xp = x + (size_t)row * 64;
            float al = sbl[col], ar = sbr[col];
#pragma unroll
            for (int k = 0; k < 64; ++k) {
                float xv = xp[k];
                al = fmaf(xv, sWl[(k << 6) + col], al);
                ar = fmaf(xv, sWr[(k << 6) + col], ar);
            }
            storef(xl, (size_t)row * 64 + col, al);
            storef(xr, (size_t)row * 64 + col, ar);
        }
    }
}

// one wave per node: online-softmax GATv2 aggregate + bias + exact GELU -> f32
template <typename ST>
__global__ __launch_bounds__(256) void k_gat(const ST* __restrict__ xl,
                                             const ST* __restrict__ xr,
                                             const int* __restrict__ rowp,
                                             const int* __restrict__ ssrc,
                                             const float* __restrict__ att,
                                             const float* __restrict__ bias,
                                             float* __restrict__ out, int n) {
    int wid = (blockIdx.x * 256 + threadIdx.x) >> 6;
    if (wid >= n) return;
    int lane = threadIdx.x & 63;
    float a = att[lane];
    float xri = loadf(xr, (size_t)wid * 64 + lane);
    int beg = rowp[wid], end = rowp[wid + 1];
    float m = -3.4e38f, denom = 0.f, acc = 0.f;
    for (int e = beg; e < end; ++e) {
        int s = ssrc[e];
        float v = loadf(xl, (size_t)s * 64 + lane);
        float t = v + xri;
        t = t > 0.f ? t : SLOPE * t;
        float le = a * t;
        le += __shfl_xor(le, 32);
        le += __shfl_xor(le, 16);
        le += __shfl_xor(le, 8);
        le += __shfl_xor(le, 4);
        le += __shfl_xor(le, 2);
        le += __shfl_xor(le, 1);
        if (le > m) {  // wave-uniform
            float sc = __expf(m - le);
            denom *= sc;
            acc *= sc;
            m = le;
        }
        float p = __expf(le - m);
        denom += p;
        acc = fmaf(p, v, acc);
    }
    float o = acc / denom + bias[lane];
    o = 0.5f * o * (1.0f + erff(o * 0.70710678118654752f));
    out[(size_t)wid * 64 + lane] = o;
}

// ---------- launch ----------

template <typename ST>
static void run_layers(const float* x0, const float* Wl, const float* bl,
                       const float* Wr, const float* br, const float* att,
                       const float* bias, ST* xl, ST* xr, const int* rowp,
                       const int* ssrc, float* xout, int N, hipStream_t stream) {
    int gat_grid = (N + 3) / 4;
    for (int l = 0; l < 3; ++l) {
        const float* xin = (l == 0) ? x0 : xout;
        k_lin2<ST><<<2048, 256, 0, stream>>>(
            xin, Wl + (size_t)l * 4096, bl + (size_t)l * 64,
            Wr + (size_t)l * 4096, br + (size_t)l * 64, xl, xr, N);
        k_gat<ST><<<gat_grid, 256, 0, stream>>>(xl, xr, rowp, ssrc,
                                                att + (size_t)l * 64,
                                                bias + (size_t)l * 64, xout, N);
    }
}

extern "C" void kernel_launch(void* const* d_in, const int* in_sizes, int n_in,
                              void* d_out, int out_size, void* d_ws, size_t ws_size,
                              hipStream_t stream) {
    (void)n_in;
    (void)out_size;
    const float* x0 = (const float*)d_in[0];
    const int* ei = (const int*)d_in[1];
    const float* Wl = (const float*)d_in[2];
    const float* bl = (const float*)d_in[3];
    const float* Wr = (const float*)d_in[4];
    const float* br = (const float*)d_in[5];
    const float* att = (const float*)d_in[6];
    const float* bias = (const float*)d_in[7];

    int N = in_sizes[0] / 64;
    int E = in_sizes[1] / 2;
    size_t ND = (size_t)N * 64;

    char* w = (char*)d_ws;
    int* flag = (int*)w;  w += 256;
    int* parts = (int*)w; w += 4096;
    int* rowp = (int*)w;  w += ((size_t)N + 8) * 4;
    int* deg = (int*)w;   w += ((size_t)N + 8) * 4;  // reused as `cur`
    int* ssrc = (int*)w;  w += ((size_t)E + 8) * 4;
    size_t head = (size_t)(w - (char*)d_ws);

    bool f32path = (ws_size >= head + 2 * ND * sizeof(float) + 4096);

    int NB = (N + 1023) / 1024;
    int nzb = (N + 255) / 256;
    int neb = (E + 255) / 256;

    k_detect<<<1, 256, 0, stream>>>(ei, 4096, flag);
    k_zero<<<nzb, 256, 0, stream>>>(deg, N);
    k_hist<<<neb, 256, 0, stream>>>(ei, E, flag, deg);
    k_scan_part<<<NB, 256, 0, stream>>>(deg, N, parts);
    k_scan_top<<<1, 64, 0, stream>>>(parts, NB, rowp, N);
    k_scan_final<<<NB, 256, 0, stream>>>(deg, N, parts, rowp);
    k_zero<<<nzb, 256, 0, stream>>>(deg, N);  // deg now serves as `cur`
    k_scatter<<<neb, 256, 0, stream>>>(ei, E, flag, rowp, deg, ssrc);

    float* xout = (float*)d_out;
    if (f32path) {
        float* xl = (float*)w;
        float* xr = xl + ND;
        run_layers<float>(x0, Wl, bl, Wr, br, att, bias, xl, xr, rowp, ssrc,
                          xout, N, stream);
    } else {
        __hip_bfloat16* xl = (__hip_bfloat16*)w;
        __hip_bfloat16* xr = xl + ND;
        run_layers<__hip_bfloat16>(x0, Wl, bl, Wr, br, att, bias, xl, xr, rowp,
                                   ssrc, xout, N, stream);
    }
}

// Round 4
// 346.213 us; speedup vs baseline: 1.5006x; 1.5006x over previous
//
#include <hip/hip_runtime.h>
#include <hip/hip_bf16.h>

#define SLOPE 0.2f

// ---------- small utils ----------

__global__ __launch_bounds__(256) void k_zero(int* __restrict__ p, int n) {
    int i = blockIdx.x * 256 + threadIdx.x;
    if (i < n) p[i] = 0;
}

// detect int64 vs int32 edge_index: odd int32 words are (nearly) all 0 iff int64
__global__ __launch_bounds__(256) void k_detect(const int* __restrict__ ei, int nwords,
                                                int* __restrict__ flag) {
    __shared__ int cnt;
    if (threadIdx.x == 0) cnt = 0;
    __syncthreads();
    int z = 0;
    for (int i = threadIdx.x; i < nwords; i += 256)
        if ((i & 1) && ei[i] == 0) z++;
    atomicAdd(&cnt, z);
    __syncthreads();
    if (threadIdx.x == 0) *flag = (cnt > nwords / 4) ? 1 : 0;
}

__device__ inline int esrc_at(const int* ei, int E, int f, int e) {
    return f ? ei[2 * e] : ei[e];
}
__device__ inline int edst_at(const int* ei, int E, int f, int e) {
    return f ? ei[2 * (E + e)] : ei[E + e];
}

// ---------- CSR build ----------

__global__ __launch_bounds__(256) void k_hist(const int* __restrict__ ei, int E,
                                              const int* __restrict__ flag,
                                              int* __restrict__ deg) {
    int e = blockIdx.x * 256 + threadIdx.x;
    if (e < E) atomicAdd(&deg[edst_at(ei, E, *flag, e)], 1);
}

__global__ __launch_bounds__(256) void k_scan_part(const int* __restrict__ deg, int n,
                                                   int* __restrict__ parts) {
    __shared__ int s[256];
    int base = blockIdx.x * 1024;
    int sum = 0;
    for (int j = threadIdx.x; j < 1024; j += 256) {
        int i = base + j;
        sum += (i < n) ? deg[i] : 0;
    }
    s[threadIdx.x] = sum;
    __syncthreads();
    for (int off = 128; off > 0; off >>= 1) {
        if (threadIdx.x < off) s[threadIdx.x] += s[threadIdx.x + off];
        __syncthreads();
    }
    if (threadIdx.x == 0) parts[blockIdx.x] = s[0];
}

__global__ __launch_bounds__(64) void k_scan_top(int* __restrict__ parts, int NB,
                                                 int* __restrict__ rowp, int n) {
    if (threadIdx.x == 0 && blockIdx.x == 0) {
        int run = 0;
        for (int b = 0; b < NB; ++b) {
            int t = parts[b];
            parts[b] = run;
            run += t;
        }
        rowp[n] = run;
    }
}

__global__ __launch_bounds__(256) void k_scan_final(const int* __restrict__ deg, int n,
                                                    const int* __restrict__ parts,
                                                    int* __restrict__ rowp) {
    __shared__ int s[256];
    int t = threadIdx.x;
    int base = blockIdx.x * 1024 + t * 4;
    int v0 = (base + 0 < n) ? deg[base + 0] : 0;
    int v1 = (base + 1 < n) ? deg[base + 1] : 0;
    int v2 = (base + 2 < n) ? deg[base + 2] : 0;
    int v3 = (base + 3 < n) ? deg[base + 3] : 0;
    int mysum = v0 + v1 + v2 + v3;
    s[t] = mysum;
    __syncthreads();
    for (int off = 1; off < 256; off <<= 1) {
        int add = (t >= off) ? s[t - off] : 0;
        __syncthreads();
        s[t] += add;
        __syncthreads();
    }
    int excl = parts[blockIdx.x] + s[t] - mysum;
    if (base + 0 < n) rowp[base + 0] = excl;
    if (base + 1 < n) rowp[base + 1] = excl + v0;
    if (base + 2 < n) rowp[base + 2] = excl + v0 + v1;
    if (base + 3 < n) rowp[base + 3] = excl + v0 + v1 + v2;
}

__global__ __launch_bounds__(256) void k_scatter(const int* __restrict__ ei, int E,
                                                 const int* __restrict__ flag,
                                                 const int* __restrict__ rowp,
                                                 int* __restrict__ cur,
                                                 int* __restrict__ ssrc) {
    int e = blockIdx.x * 256 + threadIdx.x;
    if (e < E) {
        int f = *flag;
        int i = edst_at(ei, E, f, e);
        int pos = rowp[i] + atomicAdd(&cur[i], 1);
        ssrc[pos] = esrc_at(ei, E, f, e);
    }
}

// ---------- dtype helpers ----------

__device__ inline void storef(float* p, size_t i, float v) { p[i] = v; }
__device__ inline void storef(__hip_bfloat16* p, size_t i, float v) {
    p[i] = __float2bfloat16(v);
}
__device__ inline float4 loadf4(const float* p, size_t i4) {
    return reinterpret_cast<const float4*>(p)[i4];
}
__device__ inline float4 loadf4(const __hip_bfloat16* p, size_t i4) {
    ushort4 u = reinterpret_cast<const ushort4*>(p)[i4];
    float4 r;
    r.x = __uint_as_float((unsigned)u.x << 16);
    r.y = __uint_as_float((unsigned)u.y << 16);
    r.z = __uint_as_float((unsigned)u.z << 16);
    r.w = __uint_as_float((unsigned)u.w << 16);
    return r;
}

// ---------- per-layer kernels ----------

// xl = x@Wl + bl ; xr = x@Wr + br   (D = 64), W staged in LDS
template <typename ST>
__global__ __launch_bounds__(256) void k_lin2(const float* __restrict__ x,
                                              const float* __restrict__ Wl,
                                              const float* __restrict__ bl,
                                              const float* __restrict__ Wr,
                                              const float* __restrict__ br,
                                              ST* __restrict__ xl,
                                              ST* __restrict__ xr, int n) {
    __shared__ float sWl[4096], sWr[4096], sbl[64], sbr[64];
    int t = threadIdx.x;
    for (int k = t; k < 4096; k += 256) {
        sWl[k] = Wl[k];
        sWr[k] = Wr[k];
    }
    if (t < 64) {
        sbl[t] = bl[t];
        sbr[t] = br[t];
    }
    __syncthreads();
    int col = t & 63;
    int rl = t >> 6;
    int ngroups = (n + 3) >> 2;
    for (int g = blockIdx.x; g < ngroups; g += gridDim.x) {
        int row = g * 4 + rl;
        if (row < n) {
            const float4* xp4 = reinterpret_cast<const float4*>(x + (size_t)row * 64);
            float al = sbl[col], ar = sbr[col];
#pragma unroll
            for (int k4 = 0; k4 < 16; ++k4) {
                float4 xv = xp4[k4];
                int kb = k4 << 2;
                al = fmaf(xv.x, sWl[((kb + 0) << 6) + col], al);
                ar = fmaf(xv.x, sWr[((kb + 0) << 6) + col], ar);
                al = fmaf(xv.y, sWl[((kb + 1) << 6) + col], al);
                ar = fmaf(xv.y, sWr[((kb + 1) << 6) + col], ar);
                al = fmaf(xv.z, sWl[((kb + 2) << 6) + col], al);
                ar = fmaf(xv.z, sWr[((kb + 2) << 6) + col], ar);
                al = fmaf(xv.w, sWl[((kb + 3) << 6) + col], al);
                ar = fmaf(xv.w, sWr[((kb + 3) << 6) + col], ar);
            }
            storef(xl, (size_t)row * 64 + col, al);
            storef(xr, (size_t)row * 64 + col, ar);
        }
    }
}

// one wave per node; 4 groups of 16 lanes each handle one edge slot;
// each lane holds 4 dims (float4). Online softmax across 4-edge chunks.
template <typename ST>
__global__ __launch_bounds__(256) void k_gat(const ST* __restrict__ xl,
                                             const ST* __restrict__ xr,
                                             const int* __restrict__ rowp,
                                             const int* __restrict__ ssrc,
                                             const float* __restrict__ att,
                                             const float* __restrict__ bias,
                                             float* __restrict__ out, int n) {
    int wid = (blockIdx.x * 256 + threadIdx.x) >> 6;
    if (wid >= n) return;
    int lane = threadIdx.x & 63;
    int g = lane >> 4;   // edge slot within chunk
    int q = lane & 15;   // float4 index within row
    float4 att4 = loadf4(att, q);
    float4 xr4 = loadf4(xr, (size_t)wid * 16 + q);
    int beg = rowp[wid], end = rowp[wid + 1];
    float m = -3.4e38f, denom = 0.f;
    float4 acc = {0.f, 0.f, 0.f, 0.f};
    for (int e = beg; e < end; e += 4) {
        int rem = end - e;  // >= 1
        int idx = e + (g < rem ? g : rem - 1);
        int s = ssrc[idx];
        float4 v = loadf4(xl, (size_t)s * 16 + q);
        float tx = v.x + xr4.x; tx = tx > 0.f ? tx : SLOPE * tx;
        float ty = v.y + xr4.y; ty = ty > 0.f ? ty : SLOPE * ty;
        float tz = v.z + xr4.z; tz = tz > 0.f ? tz : SLOPE * tz;
        float tw = v.w + xr4.w; tw = tw > 0.f ? tw : SLOPE * tw;
        float l = fmaf(att4.x, tx, fmaf(att4.y, ty, fmaf(att4.z, tz, att4.w * tw)));
        l += __shfl_xor(l, 1);
        l += __shfl_xor(l, 2);
        l += __shfl_xor(l, 4);
        l += __shfl_xor(l, 8);
        if (g >= rem) l = -3.4e38f;  // mask duplicate slots in tail chunk
        float mx = fmaxf(l, __shfl_xor(l, 16));
        mx = fmaxf(mx, __shfl_xor(mx, 32));
        if (mx > m) {  // wave-uniform
            float sc = __expf(m - mx);
            denom *= sc;
            acc.x *= sc; acc.y *= sc; acc.z *= sc; acc.w *= sc;
            m = mx;
        }
        float p = __expf(l - m);  // 0 for masked slots
        denom += p;
        acc.x = fmaf(p, v.x, acc.x);
        acc.y = fmaf(p, v.y, acc.y);
        acc.z = fmaf(p, v.z, acc.z);
        acc.w = fmaf(p, v.w, acc.w);
    }
    // combine the 4 groups' partials
    denom += __shfl_xor(denom, 16);
    denom += __shfl_xor(denom, 32);
    acc.x += __shfl_xor(acc.x, 16); acc.x += __shfl_xor(acc.x, 32);
    acc.y += __shfl_xor(acc.y, 16); acc.y += __shfl_xor(acc.y, 32);
    acc.z += __shfl_xor(acc.z, 16); acc.z += __shfl_xor(acc.z, 32);
    acc.w += __shfl_xor(acc.w, 16); acc.w += __shfl_xor(acc.w, 32);
    if (g == 0) {
        float4 b4 = loadf4(bias, q);
        float inv = 1.f / denom;
        float4 o;
        o.x = acc.x * inv + b4.x;
        o.y = acc.y * inv + b4.y;
        o.z = acc.z * inv + b4.z;
        o.w = acc.w * inv + b4.w;
        o.x = 0.5f * o.x * (1.0f + erff(o.x * 0.70710678118654752f));
        o.y = 0.5f * o.y * (1.0f + erff(o.y * 0.70710678118654752f));
        o.z = 0.5f * o.z * (1.0f + erff(o.z * 0.70710678118654752f));
        o.w = 0.5f * o.w * (1.0f + erff(o.w * 0.70710678118654752f));
        reinterpret_cast<float4*>(out + (size_t)wid * 64)[q] = o;
    }
}

// ---------- launch ----------

template <typename ST>
static void run_layers(const float* x0, const float* Wl, const float* bl,
                       const float* Wr, const float* br, const float* att,
                       const float* bias, ST* xl, ST* xr, const int* rowp,
                       const int* ssrc, float* xout, int N, hipStream_t stream) {
    int gat_grid = (N + 3) / 4;
    for (int l = 0; l < 3; ++l) {
        const float* xin = (l == 0) ? x0 : xout;
        k_lin2<ST><<<2048, 256, 0, stream>>>(
            xin, Wl + (size_t)l * 4096, bl + (size_t)l * 64,
            Wr + (size_t)l * 4096, br + (size_t)l * 64, xl, xr, N);
        k_gat<ST><<<gat_grid, 256, 0, stream>>>(xl, xr, rowp, ssrc,
                                                att + (size_t)l * 64,
                                                bias + (size_t)l * 64, xout, N);
    }
}

extern "C" void kernel_launch(void* const* d_in, const int* in_sizes, int n_in,
                              void* d_out, int out_size, void* d_ws, size_t ws_size,
                              hipStream_t stream) {
    (void)n_in;
    (void)out_size;
    const float* x0 = (const float*)d_in[0];
    const int* ei = (const int*)d_in[1];
    const float* Wl = (const float*)d_in[2];
    const float* bl = (const float*)d_in[3];
    const float* Wr = (const float*)d_in[4];
    const float* br = (const float*)d_in[5];
    const float* att = (const float*)d_in[6];
    const float* bias = (const float*)d_in[7];

    int N = in_sizes[0] / 64;
    int E = in_sizes[1] / 2;
    size_t ND = (size_t)N * 64;

    char* w = (char*)d_ws;
    int* flag = (int*)w;  w += 256;
    int* parts = (int*)w; w += 4096;
    int* rowp = (int*)w;  w += ((size_t)N + 8) * 4;
    int* deg = (int*)w;   w += ((size_t)N + 8) * 4;  // reused as `cur`
    int* ssrc = (int*)w;  w += ((size_t)E + 8) * 4;
    size_t head = (size_t)(w - (char*)d_ws);

    bool f32path = (ws_size >= head + 2 * ND * sizeof(float) + 4096);

    int NB = (N + 1023) / 1024;
    int nzb = (N + 255) / 256;
    int neb = (E + 255) / 256;

    k_detect<<<1, 256, 0, stream>>>(ei, 4096, flag);
    k_zero<<<nzb, 256, 0, stream>>>(deg, N);
    k_hist<<<neb, 256, 0, stream>>>(ei, E, flag, deg);
    k_scan_part<<<NB, 256, 0, stream>>>(deg, N, parts);
    k_scan_top<<<1, 64, 0, stream>>>(parts, NB, rowp, N);
    k_scan_final<<<NB, 256, 0, stream>>>(deg, N, parts, rowp);
    k_zero<<<nzb, 256, 0, stream>>>(deg, N);  // deg now serves as `cur`
    k_scatter<<<neb, 256, 0, stream>>>(ei, E, flag, rowp, deg, ssrc);

    float* xout = (float*)d_out;
    if (f32path) {
        float* xl = (float*)w;
        float* xr = xl + ND;
        run_layers<float>(x0, Wl, bl, Wr, br, att, bias, xl, xr, rowp, ssrc,
                          xout, N, stream);
    } else {
        __hip_bfloat16* xl = (__hip_bfloat16*)w;
        __hip_bfloat16* xr = xl + ND;
        run_layers<__hip_bfloat16>(x0, Wl, bl, Wr, br, att, bias, xl, xr, rowp,
                                   ssrc, xout, N, stream);
    }
}

// Round 5
// 313.336 us; speedup vs baseline: 1.6581x; 1.1049x over previous
//
#include <hip/hip_runtime.h>
#include <hip/hip_bf16.h>

#define SLOPE 0.2f

// ---------- small utils ----------

__global__ __launch_bounds__(256) void k_zero(int* __restrict__ p, int n) {
    int i = blockIdx.x * 256 + threadIdx.x;
    if (i < n) p[i] = 0;
}

// detect int64 vs int32 edge_index: odd int32 words are (nearly) all 0 iff int64
__global__ __launch_bounds__(256) void k_detect(const int* __restrict__ ei, int nwords,
                                                int* __restrict__ flag) {
    __shared__ int cnt;
    if (threadIdx.x == 0) cnt = 0;
    __syncthreads();
    int z = 0;
    for (int i = threadIdx.x; i < nwords; i += 256)
        if ((i & 1) && ei[i] == 0) z++;
    atomicAdd(&cnt, z);
    __syncthreads();
    if (threadIdx.x == 0) *flag = (cnt > nwords / 4) ? 1 : 0;
}

__device__ inline int esrc_at(const int* ei, int E, int f, int e) {
    return f ? ei[2 * e] : ei[e];
}
__device__ inline int edst_at(const int* ei, int E, int f, int e) {
    return f ? ei[2 * (E + e)] : ei[E + e];
}

// ---------- CSR build ----------

__global__ __launch_bounds__(256) void k_hist(const int* __restrict__ ei, int E,
                                              const int* __restrict__ flag,
                                              int* __restrict__ deg) {
    int e = blockIdx.x * 256 + threadIdx.x;
    if (e < E) atomicAdd(&deg[edst_at(ei, E, *flag, e)], 1);
}

__global__ __launch_bounds__(256) void k_scan_part(const int* __restrict__ deg, int n,
                                                   int* __restrict__ parts) {
    __shared__ int s[256];
    int base = blockIdx.x * 1024;
    int sum = 0;
    for (int j = threadIdx.x; j < 1024; j += 256) {
        int i = base + j;
        sum += (i < n) ? deg[i] : 0;
    }
    s[threadIdx.x] = sum;
    __syncthreads();
    for (int off = 128; off > 0; off >>= 1) {
        if (threadIdx.x < off) s[threadIdx.x] += s[threadIdx.x + off];
        __syncthreads();
    }
    if (threadIdx.x == 0) parts[blockIdx.x] = s[0];
}

__global__ __launch_bounds__(64) void k_scan_top(int* __restrict__ parts, int NB,
                                                 int* __restrict__ rowp, int n) {
    if (threadIdx.x == 0 && blockIdx.x == 0) {
        int run = 0;
        for (int b = 0; b < NB; ++b) {
            int t = parts[b];
            parts[b] = run;
            run += t;
        }
        rowp[n] = run;
    }
}

__global__ __launch_bounds__(256) void k_scan_final(const int* __restrict__ deg, int n,
                                                    const int* __restrict__ parts,
                                                    int* __restrict__ rowp) {
    __shared__ int s[256];
    int t = threadIdx.x;
    int base = blockIdx.x * 1024 + t * 4;
    int v0 = (base + 0 < n) ? deg[base + 0] : 0;
    int v1 = (base + 1 < n) ? deg[base + 1] : 0;
    int v2 = (base + 2 < n) ? deg[base + 2] : 0;
    int v3 = (base + 3 < n) ? deg[base + 3] : 0;
    int mysum = v0 + v1 + v2 + v3;
    s[t] = mysum;
    __syncthreads();
    for (int off = 1; off < 256; off <<= 1) {
        int add = (t >= off) ? s[t - off] : 0;
        __syncthreads();
        s[t] += add;
        __syncthreads();
    }
    int excl = parts[blockIdx.x] + s[t] - mysum;
    if (base + 0 < n) rowp[base + 0] = excl;
    if (base + 1 < n) rowp[base + 1] = excl + v0;
    if (base + 2 < n) rowp[base + 2] = excl + v0 + v1;
    if (base + 3 < n) rowp[base + 3] = excl + v0 + v1 + v2;
}

__global__ __launch_bounds__(256) void k_scatter(const int* __restrict__ ei, int E,
                                                 const int* __restrict__ flag,
                                                 const int* __restrict__ rowp,
                                                 int* __restrict__ cur,
                                                 int* __restrict__ ssrc) {
    int e = blockIdx.x * 256 + threadIdx.x;
    if (e < E) {
        int f = *flag;
        int i = edst_at(ei, E, f, e);
        int pos = rowp[i] + atomicAdd(&cur[i], 1);
        ssrc[pos] = esrc_at(ei, E, f, e);
    }
}

// ---------- dtype helpers ----------

__device__ inline void storef(float* p, size_t i, float v) { p[i] = v; }
__device__ inline void storef(__hip_bfloat16* p, size_t i, float v) {
    p[i] = __float2bfloat16(v);
}

// load 8 consecutive dims (q-th 8-dim slice) of row `row` (row stride 64 elems)
__device__ inline void load8(const float* p, size_t row, int q, float v[8]) {
    const float4* b = reinterpret_cast<const float4*>(p + row * 64);
    float4 x = b[q * 2], y = b[q * 2 + 1];
    v[0] = x.x; v[1] = x.y; v[2] = x.z; v[3] = x.w;
    v[4] = y.x; v[5] = y.y; v[6] = y.z; v[7] = y.w;
}
__device__ inline void load8(const __hip_bfloat16* p, size_t row, int q, float v[8]) {
    uint4 u = reinterpret_cast<const uint4*>(p + row * 64)[q];
    v[0] = __uint_as_float(u.x << 16);
    v[1] = __uint_as_float(u.x & 0xffff0000u);
    v[2] = __uint_as_float(u.y << 16);
    v[3] = __uint_as_float(u.y & 0xffff0000u);
    v[4] = __uint_as_float(u.z << 16);
    v[5] = __uint_as_float(u.z & 0xffff0000u);
    v[6] = __uint_as_float(u.w << 16);
    v[7] = __uint_as_float(u.w & 0xffff0000u);
}

// ---------- per-layer kernels ----------

// xl = x@Wl + bl ; xr = x@Wr + br   (D = 64), W staged in LDS
template <typename ST, typename SR>
__global__ __launch_bounds__(256) void k_lin2(const float* __restrict__ x,
                                              const float* __restrict__ Wl,
                                              const float* __restrict__ bl,
                                              const float* __restrict__ Wr,
                                              const float* __restrict__ br,
                                              ST* __restrict__ xl,
                                              SR* __restrict__ xr, int n) {
    __shared__ float sWl[4096], sWr[4096], sbl[64], sbr[64];
    int t = threadIdx.x;
    for (int k = t; k < 4096; k += 256) {
        sWl[k] = Wl[k];
        sWr[k] = Wr[k];
    }
    if (t < 64) {
        sbl[t] = bl[t];
        sbr[t] = br[t];
    }
    __syncthreads();
    int col = t & 63;
    int rl = t >> 6;
    int ngroups = (n + 3) >> 2;
    for (int g = blockIdx.x; g < ngroups; g += gridDim.x) {
        int row = g * 4 + rl;
        if (row < n) {
            const float4* xp4 = reinterpret_cast<const float4*>(x + (size_t)row * 64);
            float al = sbl[col], ar = sbr[col];
#pragma unroll
            for (int k4 = 0; k4 < 16; ++k4) {
                float4 xv = xp4[k4];
                int kb = k4 << 2;
                al = fmaf(xv.x, sWl[((kb + 0) << 6) + col], al);
                ar = fmaf(xv.x, sWr[((kb + 0) << 6) + col], ar);
                al = fmaf(xv.y, sWl[((kb + 1) << 6) + col], al);
                ar = fmaf(xv.y, sWr[((kb + 1) << 6) + col], ar);
                al = fmaf(xv.z, sWl[((kb + 2) << 6) + col], al);
                ar = fmaf(xv.z, sWr[((kb + 2) << 6) + col], ar);
                al = fmaf(xv.w, sWl[((kb + 3) << 6) + col], al);
                ar = fmaf(xv.w, sWr[((kb + 3) << 6) + col], ar);
            }
            storef(xl, (size_t)row * 64 + col, al);
            storef(xr, (size_t)row * 64 + col, ar);
        }
    }
}

// one wave per node; 8 groups of 8 lanes, each group owns one edge slot;
// lane holds 8 dims. Per-group branchless online softmax, merged at the end.
template <typename ST, typename SR>
__global__ __launch_bounds__(256) void k_gat(const ST* __restrict__ xl,
                                             const SR* __restrict__ xr,
                                             const int* __restrict__ rowp,
                                             const int* __restrict__ ssrc,
                                             const float* __restrict__ att,
                                             const float* __restrict__ bias,
                                             float* __restrict__ out, int n) {
    int wid = (blockIdx.x * 256 + threadIdx.x) >> 6;
    if (wid >= n) return;
    int lane = threadIdx.x & 63;
    int g = lane >> 3;  // edge slot within chunk (0..7)
    int q = lane & 7;   // 8-dim slice within row (0..7)
    float a[8], r[8];
    load8(att, 0, q, a);
    load8(xr, (size_t)wid, q, r);
    int beg = rowp[wid], end = rowp[wid + 1];
    float m = -3.4e38f, denom = 0.f;
    float acc[8] = {0.f, 0.f, 0.f, 0.f, 0.f, 0.f, 0.f, 0.f};
    for (int e = beg; e < end; e += 8) {
        int rem = end - e;  // >= 1
        bool valid = (g < rem);
        int idx = e + (valid ? g : rem - 1);
        int s = ssrc[idx];
        float v[8];
        load8(xl, (size_t)s, q, v);
        float l = 0.f;
#pragma unroll
        for (int j = 0; j < 8; ++j) {
            float tj = v[j] + r[j];
            tj = tj > 0.f ? tj : SLOPE * tj;
            l = fmaf(a[j], tj, l);
        }
        l += __shfl_xor(l, 1);
        l += __shfl_xor(l, 2);
        l += __shfl_xor(l, 4);
        float mnew = valid ? fmaxf(m, l) : m;
        float sc = __expf(m - mnew);           // 0 on first valid chunk, 1 if no change
        float p = valid ? __expf(l - mnew) : 0.f;
        denom = denom * sc + p;
#pragma unroll
        for (int j = 0; j < 8; ++j) acc[j] = fmaf(acc[j], sc, p * v[j]);
        m = mnew;
    }
    // merge the 8 per-group states
    float mt = m;
    mt = fmaxf(mt, __shfl_xor(mt, 8));
    mt = fmaxf(mt, __shfl_xor(mt, 16));
    mt = fmaxf(mt, __shfl_xor(mt, 32));
    float sc = __expf(m - mt);  // 0 for never-valid groups (m=-3.4e38)
    denom *= sc;
    denom += __shfl_xor(denom, 8);
    denom += __shfl_xor(denom, 16);
    denom += __shfl_xor(denom, 32);
#pragma unroll
    for (int j = 0; j < 8; ++j) {
        acc[j] *= sc;
        acc[j] += __shfl_xor(acc[j], 8);
        acc[j] += __shfl_xor(acc[j], 16);
        acc[j] += __shfl_xor(acc[j], 32);
    }
    if (g == 0) {
        float b[8];
        load8(bias, 0, q, b);
        float inv = 1.f / denom;
        float o[8];
#pragma unroll
        for (int j = 0; j < 8; ++j) {
            float oj = acc[j] * inv + b[j];
            o[j] = 0.5f * oj * (1.0f + erff(oj * 0.70710678118654752f));
        }
        float4* ob = reinterpret_cast<float4*>(out + (size_t)wid * 64);
        ob[q * 2] = make_float4(o[0], o[1], o[2], o[3]);
        ob[q * 2 + 1] = make_float4(o[4], o[5], o[6], o[7]);
    }
}

// ---------- launch ----------

template <typename ST, typename SR>
static void run_layers(const float* x0, const float* Wl, const float* bl,
                       const float* Wr, const float* br, const float* att,
                       const float* bias, ST* xl, SR* xr, const int* rowp,
                       const int* ssrc, float* xout, int N, hipStream_t stream) {
    int gat_grid = (N + 3) / 4;
    for (int l = 0; l < 3; ++l) {
        const float* xin = (l == 0) ? x0 : xout;
        k_lin2<ST, SR><<<2048, 256, 0, stream>>>(
            xin, Wl + (size_t)l * 4096, bl + (size_t)l * 64,
            Wr + (size_t)l * 4096, br + (size_t)l * 64, xl, xr, N);
        k_gat<ST, SR><<<gat_grid, 256, 0, stream>>>(xl, xr, rowp, ssrc,
                                                    att + (size_t)l * 64,
                                                    bias + (size_t)l * 64, xout, N);
    }
}

extern "C" void kernel_launch(void* const* d_in, const int* in_sizes, int n_in,
                              void* d_out, int out_size, void* d_ws, size_t ws_size,
                              hipStream_t stream) {
    (void)n_in;
    (void)out_size;
    const float* x0 = (const float*)d_in[0];
    const int* ei = (const int*)d_in[1];
    const float* Wl = (const float*)d_in[2];
    const float* bl = (const float*)d_in[3];
    const float* Wr = (const float*)d_in[4];
    const float* br = (const float*)d_in[5];
    const float* att = (const float*)d_in[6];
    const float* bias = (const float*)d_in[7];

    int N = in_sizes[0] / 64;
    int E = in_sizes[1] / 2;
    size_t ND = (size_t)N * 64;

    char* w = (char*)d_ws;
    int* flag = (int*)w;  w += 256;
    int* parts = (int*)w; w += 4096;
    int* rowp = (int*)w;  w += ((size_t)N + 8) * 4;
    int* deg = (int*)w;   w += ((size_t)N + 8) * 4;
    int* cur = (int*)w;   w += ((size_t)N + 8) * 4;  // adjacent to deg: zeroed together
    int* ssrc = (int*)w;  w += ((size_t)E + 8) * 4;
    size_t head = (size_t)(w - (char*)d_ws);

    // primary: xl bf16 (gathered), xr f32 (streamed once)
    bool big = (ws_size >= head + ND * 2 + ND * 4 + 4096);

    int NB = (N + 1023) / 1024;
    int neb = (E + 255) / 256;
    int nz2 = (2 * (N + 8) + 255) / 256;

    k_detect<<<1, 256, 0, stream>>>(ei, 4096, flag);
    k_zero<<<nz2, 256, 0, stream>>>(deg, 2 * (N + 8));  // deg + cur in one go
    k_hist<<<neb, 256, 0, stream>>>(ei, E, flag, deg);
    k_scan_part<<<NB, 256, 0, stream>>>(deg, N, parts);
    k_scan_top<<<1, 64, 0, stream>>>(parts, NB, rowp, N);
    k_scan_final<<<NB, 256, 0, stream>>>(deg, N, parts, rowp);
    k_scatter<<<neb, 256, 0, stream>>>(ei, E, flag, rowp, cur, ssrc);

    float* xout = (float*)d_out;
    if (big) {
        __hip_bfloat16* xl = (__hip_bfloat16*)w;
        float* xr = (float*)(w + ND * 2);
        run_layers<__hip_bfloat16, float>(x0, Wl, bl, Wr, br, att, bias, xl, xr,
                                          rowp, ssrc, xout, N, stream);
    } else {
        __hip_bfloat16* xl = (__hip_bfloat16*)w;
        __hip_bfloat16* xr = xl + ND;
        run_layers<__hip_bfloat16, __hip_bfloat16>(x0, Wl, bl, Wr, br, att, bias,
                                                   xl, xr, rowp, ssrc, xout, N,
                                                   stream);
    }
}

// Round 6
// 277.080 us; speedup vs baseline: 1.8751x; 1.1309x over previous
//
#include <hip/hip_runtime.h>
#include <hip/hip_bf16.h>

#define SLOPE 0.2f

// ---------- small utils ----------

__global__ __launch_bounds__(256) void k_zero(int* __restrict__ p, int n) {
    int i = blockIdx.x * 256 + threadIdx.x;
    if (i < n) p[i] = 0;
}

// detect int64 vs int32 edge_index: odd int32 words are (nearly) all 0 iff int64
__global__ __launch_bounds__(256) void k_detect(const int* __restrict__ ei, int nwords,
                                                int* __restrict__ flag) {
    __shared__ int cnt;
    if (threadIdx.x == 0) cnt = 0;
    __syncthreads();
    int z = 0;
    for (int i = threadIdx.x; i < nwords; i += 256)
        if ((i & 1) && ei[i] == 0) z++;
    atomicAdd(&cnt, z);
    __syncthreads();
    if (threadIdx.x == 0) *flag = (cnt > nwords / 4) ? 1 : 0;
}

__device__ inline int esrc_at(const int* ei, int E, int f, int e) {
    return f ? ei[2 * e] : ei[e];
}
__device__ inline int edst_at(const int* ei, int E, int f, int e) {
    return f ? ei[2 * (E + e)] : ei[E + e];
}

// ---------- CSR build ----------

// histogram + per-edge rank (arrival order within its dst bucket)
__global__ __launch_bounds__(256) void k_hist(const int* __restrict__ ei, int E,
                                              const int* __restrict__ flag,
                                              int* __restrict__ deg,
                                              int* __restrict__ rank) {
    int e = blockIdx.x * 256 + threadIdx.x;
    if (e < E) rank[e] = atomicAdd(&deg[edst_at(ei, E, *flag, e)], 1);
}

__global__ __launch_bounds__(256) void k_scan_part(const int* __restrict__ deg, int n,
                                                   int* __restrict__ parts) {
    __shared__ int s[256];
    int base = blockIdx.x * 1024;
    int sum = 0;
    for (int j = threadIdx.x; j < 1024; j += 256) {
        int i = base + j;
        sum += (i < n) ? deg[i] : 0;
    }
    s[threadIdx.x] = sum;
    __syncthreads();
    for (int off = 128; off > 0; off >>= 1) {
        if (threadIdx.x < off) s[threadIdx.x] += s[threadIdx.x + off];
        __syncthreads();
    }
    if (threadIdx.x == 0) parts[blockIdx.x] = s[0];
}

__global__ __launch_bounds__(64) void k_scan_top(int* __restrict__ parts, int NB,
                                                 int* __restrict__ rowp, int n) {
    if (threadIdx.x == 0 && blockIdx.x == 0) {
        int run = 0;
        for (int b = 0; b < NB; ++b) {
            int t = parts[b];
            parts[b] = run;
            run += t;
        }
        rowp[n] = run;
    }
}

__global__ __launch_bounds__(256) void k_scan_final(const int* __restrict__ deg, int n,
                                                    const int* __restrict__ parts,
                                                    int* __restrict__ rowp) {
    __shared__ int s[256];
    int t = threadIdx.x;
    int base = blockIdx.x * 1024 + t * 4;
    int v0 = (base + 0 < n) ? deg[base + 0] : 0;
    int v1 = (base + 1 < n) ? deg[base + 1] : 0;
    int v2 = (base + 2 < n) ? deg[base + 2] : 0;
    int v3 = (base + 3 < n) ? deg[base + 3] : 0;
    int mysum = v0 + v1 + v2 + v3;
    s[t] = mysum;
    __syncthreads();
    for (int off = 1; off < 256; off <<= 1) {
        int add = (t >= off) ? s[t - off] : 0;
        __syncthreads();
        s[t] += add;
        __syncthreads();
    }
    int excl = parts[blockIdx.x] + s[t] - mysum;
    if (base + 0 < n) rowp[base + 0] = excl;
    if (base + 1 < n) rowp[base + 1] = excl + v0;
    if (base + 2 < n) rowp[base + 2] = excl + v0 + v1;
    if (base + 3 < n) rowp[base + 3] = excl + v0 + v1 + v2;
}

// atomic-free scatter: position = rowp[dst] + rank[e]
template <typename IT>
__global__ __launch_bounds__(256) void k_scatter(const int* __restrict__ ei, int E,
                                                 const int* __restrict__ flag,
                                                 const int* __restrict__ rowp,
                                                 const int* __restrict__ rank,
                                                 IT* __restrict__ ssrc) {
    int e = blockIdx.x * 256 + threadIdx.x;
    if (e < E) {
        int f = *flag;
        int i = edst_at(ei, E, f, e);
        ssrc[rowp[i] + rank[e]] = (IT)esrc_at(ei, E, f, e);
    }
}

// ---------- dtype helpers ----------

__device__ inline void storef(float* p, size_t i, float v) { p[i] = v; }
__device__ inline void storef(__hip_bfloat16* p, size_t i, float v) {
    p[i] = __float2bfloat16(v);
}

// load 8 consecutive dims (q-th 8-dim slice) of row `row` (row stride 64 elems)
__device__ inline void load8(const float* p, size_t row, int q, float v[8]) {
    const float4* b = reinterpret_cast<const float4*>(p + row * 64);
    float4 x = b[q * 2], y = b[q * 2 + 1];
    v[0] = x.x; v[1] = x.y; v[2] = x.z; v[3] = x.w;
    v[4] = y.x; v[5] = y.y; v[6] = y.z; v[7] = y.w;
}
__device__ inline void load8(const __hip_bfloat16* p, size_t row, int q, float v[8]) {
    uint4 u = reinterpret_cast<const uint4*>(p + row * 64)[q];
    v[0] = __uint_as_float(u.x << 16);
    v[1] = __uint_as_float(u.x & 0xffff0000u);
    v[2] = __uint_as_float(u.y << 16);
    v[3] = __uint_as_float(u.y & 0xffff0000u);
    v[4] = __uint_as_float(u.z << 16);
    v[5] = __uint_as_float(u.z & 0xffff0000u);
    v[6] = __uint_as_float(u.w << 16);
    v[7] = __uint_as_float(u.w & 0xffff0000u);
}

// ---------- per-layer kernels ----------

// xl = x@Wl + bl ; xr = x@Wr + br   (D = 64), W staged in LDS
template <typename ST, typename SR>
__global__ __launch_bounds__(256) void k_lin2(const float* __restrict__ x,
                                              const float* __restrict__ Wl,
                                              const float* __restrict__ bl,
                                              const float* __restrict__ Wr,
                                              const float* __restrict__ br,
                                              ST* __restrict__ xl,
                                              SR* __restrict__ xr, int n) {
    __shared__ float sWl[4096], sWr[4096], sbl[64], sbr[64];
    int t = threadIdx.x;
    for (int k = t; k < 4096; k += 256) {
        sWl[k] = Wl[k];
        sWr[k] = Wr[k];
    }
    if (t < 64) {
        sbl[t] = bl[t];
        sbr[t] = br[t];
    }
    __syncthreads();
    int col = t & 63;
    int rl = t >> 6;
    int ngroups = (n + 3) >> 2;
    for (int g = blockIdx.x; g < ngroups; g += gridDim.x) {
        int row = g * 4 + rl;
        if (row < n) {
            const float4* xp4 = reinterpret_cast<const float4*>(x + (size_t)row * 64);
            float al = sbl[col], ar = sbr[col];
#pragma unroll
            for (int k4 = 0; k4 < 16; ++k4) {
                float4 xv = xp4[k4];
                int kb = k4 << 2;
                al = fmaf(xv.x, sWl[((kb + 0) << 6) + col], al);
                ar = fmaf(xv.x, sWr[((kb + 0) << 6) + col], ar);
                al = fmaf(xv.y, sWl[((kb + 1) << 6) + col], al);
                ar = fmaf(xv.y, sWr[((kb + 1) << 6) + col], ar);
                al = fmaf(xv.z, sWl[((kb + 2) << 6) + col], al);
                ar = fmaf(xv.z, sWr[((kb + 2) << 6) + col], ar);
                al = fmaf(xv.w, sWl[((kb + 3) << 6) + col], al);
                ar = fmaf(xv.w, sWr[((kb + 3) << 6) + col], ar);
            }
            storef(xl, (size_t)row * 64 + col, al);
            storef(xr, (size_t)row * 64 + col, ar);
        }
    }
}

// one wave per node; 8 groups of 8 lanes, each group owns one edge slot;
// lane holds 8 dims. Per-group branchless online softmax, merged at the end.
template <typename ST, typename SR, typename IT>
__global__ __launch_bounds__(256) void k_gat(const ST* __restrict__ xl,
                                             const SR* __restrict__ xr,
                                             const int* __restrict__ rowp,
                                             const IT* __restrict__ ssrc,
                                             const float* __restrict__ att,
                                             const float* __restrict__ bias,
                                             float* __restrict__ out, int n) {
    int wid = (blockIdx.x * 256 + threadIdx.x) >> 6;
    if (wid >= n) return;
    int lane = threadIdx.x & 63;
    int g = lane >> 3;  // edge slot within chunk (0..7)
    int q = lane & 7;   // 8-dim slice within row (0..7)
    float a[8], r[8];
    load8(att, 0, q, a);
    load8(xr, (size_t)wid, q, r);
    int beg = rowp[wid], end = rowp[wid + 1];
    float m = -3.4e38f, denom = 0.f;
    float acc[8] = {0.f, 0.f, 0.f, 0.f, 0.f, 0.f, 0.f, 0.f};
    for (int e = beg; e < end; e += 8) {
        int rem = end - e;  // >= 1
        bool valid = (g < rem);
        int idx = e + (valid ? g : rem - 1);
        int s = (int)ssrc[idx];
        float v[8];
        load8(xl, (size_t)s, q, v);
        float l = 0.f;
#pragma unroll
        for (int j = 0; j < 8; ++j) {
            float tj = v[j] + r[j];
            tj = tj > 0.f ? tj : SLOPE * tj;
            l = fmaf(a[j], tj, l);
        }
        l += __shfl_xor(l, 1);
        l += __shfl_xor(l, 2);
        l += __shfl_xor(l, 4);
        float mnew = valid ? fmaxf(m, l) : m;
        float sc = __expf(m - mnew);           // 0 on first valid chunk, 1 if no change
        float p = valid ? __expf(l - mnew) : 0.f;
        denom = denom * sc + p;
#pragma unroll
        for (int j = 0; j < 8; ++j) acc[j] = fmaf(acc[j], sc, p * v[j]);
        m = mnew;
    }
    // merge the 8 per-group states
    float mt = m;
    mt = fmaxf(mt, __shfl_xor(mt, 8));
    mt = fmaxf(mt, __shfl_xor(mt, 16));
    mt = fmaxf(mt, __shfl_xor(mt, 32));
    float sc = __expf(m - mt);  // 0 for never-valid groups (m=-3.4e38)
    denom *= sc;
    denom += __shfl_xor(denom, 8);
    denom += __shfl_xor(denom, 16);
    denom += __shfl_xor(denom, 32);
#pragma unroll
    for (int j = 0; j < 8; ++j) {
        acc[j] *= sc;
        acc[j] += __shfl_xor(acc[j], 8);
        acc[j] += __shfl_xor(acc[j], 16);
        acc[j] += __shfl_xor(acc[j], 32);
    }
    if (g == 0) {
        float b[8];
        load8(bias, 0, q, b);
        float inv = 1.f / denom;
        float o[8];
#pragma unroll
        for (int j = 0; j < 8; ++j) {
            float oj = acc[j] * inv + b[j];
            o[j] = 0.5f * oj * (1.0f + erff(oj * 0.70710678118654752f));
        }
        float4* ob = reinterpret_cast<float4*>(out + (size_t)wid * 64);
        ob[q * 2] = make_float4(o[0], o[1], o[2], o[3]);
        ob[q * 2 + 1] = make_float4(o[4], o[5], o[6], o[7]);
    }
}

// ---------- launch ----------

template <typename ST, typename SR, typename IT>
static void run_layers(const float* x0, const float* Wl, const float* bl,
                       const float* Wr, const float* br, const float* att,
                       const float* bias, ST* xl, SR* xr, const int* rowp,
                       const IT* ssrc, float* xout, int N, hipStream_t stream) {
    int gat_grid = (N + 3) / 4;
    for (int l = 0; l < 3; ++l) {
        const float* xin = (l == 0) ? x0 : xout;
        k_lin2<ST, SR><<<2048, 256, 0, stream>>>(
            xin, Wl + (size_t)l * 4096, bl + (size_t)l * 64,
            Wr + (size_t)l * 4096, br + (size_t)l * 64, xl, xr, N);
        k_gat<ST, SR, IT><<<gat_grid, 256, 0, stream>>>(xl, xr, rowp, ssrc,
                                                        att + (size_t)l * 64,
                                                        bias + (size_t)l * 64,
                                                        xout, N);
    }
}

extern "C" void kernel_launch(void* const* d_in, const int* in_sizes, int n_in,
                              void* d_out, int out_size, void* d_ws, size_t ws_size,
                              hipStream_t stream) {
    (void)n_in;
    (void)out_size;
    const float* x0 = (const float*)d_in[0];
    const int* ei = (const int*)d_in[1];
    const float* Wl = (const float*)d_in[2];
    const float* bl = (const float*)d_in[3];
    const float* Wr = (const float*)d_in[4];
    const float* br = (const float*)d_in[5];
    const float* att = (const float*)d_in[6];
    const float* bias = (const float*)d_in[7];

    int N = in_sizes[0] / 64;
    int E = in_sizes[1] / 2;
    size_t ND = (size_t)N * 64;

    char* w = (char*)d_ws;
    int* flag = (int*)w;       w += 256;
    int* parts = (int*)w;      w += 4096;
    int* rowp = (int*)w;       w += ((size_t)N + 8) * 4;
    int* deg = (int*)w;        w += ((size_t)N + 8) * 4;
    int* rank = (int*)w;       w += ((size_t)E + 8) * 4;
    unsigned short* ssrc16 = (unsigned short*)w;
    int* ssrc32 = (int*)w;     w += ((size_t)E + 8) * 4;  // reserve int-sized
    size_t head = (size_t)(w - (char*)d_ws);

    // primary: xl bf16 (gathered), xr f32 (streamed once)
    bool big = (ws_size >= head + ND * 2 + ND * 4 + 4096);
    bool small_ids = (N <= 65535);

    int NB = (N + 1023) / 1024;
    int neb = (E + 255) / 256;
    int nzb = (N + 255) / 256;

    k_detect<<<1, 256, 0, stream>>>(ei, 4096, flag);
    k_zero<<<nzb, 256, 0, stream>>>(deg, N);
    k_hist<<<neb, 256, 0, stream>>>(ei, E, flag, deg, rank);
    k_scan_part<<<NB, 256, 0, stream>>>(deg, N, parts);
    k_scan_top<<<1, 64, 0, stream>>>(parts, NB, rowp, N);
    k_scan_final<<<NB, 256, 0, stream>>>(deg, N, parts, rowp);
    if (small_ids)
        k_scatter<unsigned short><<<neb, 256, 0, stream>>>(ei, E, flag, rowp, rank, ssrc16);
    else
        k_scatter<int><<<neb, 256, 0, stream>>>(ei, E, flag, rowp, rank, ssrc32);

    float* xout = (float*)d_out;
    if (big) {
        __hip_bfloat16* xl = (__hip_bfloat16*)w;
        float* xr = (float*)(w + ND * 2);
        if (small_ids)
            run_layers<__hip_bfloat16, float, unsigned short>(
                x0, Wl, bl, Wr, br, att, bias, xl, xr, rowp, ssrc16, xout, N, stream);
        else
            run_layers<__hip_bfloat16, float, int>(
                x0, Wl, bl, Wr, br, att, bias, xl, xr, rowp, ssrc32, xout, N, stream);
    } else {
        __hip_bfloat16* xl = (__hip_bfloat16*)w;
        __hip_bfloat16* xr = xl + ND;
        if (small_ids)
            run_layers<__hip_bfloat16, __hip_bfloat16, unsigned short>(
                x0, Wl, bl, Wr, br, att, bias, xl, xr, rowp, ssrc16, xout, N, stream);
        else
            run_layers<__hip_bfloat16, __hip_bfloat16, int>(
                x0, Wl, bl, Wr, br, att, bias, xl, xr, rowp, ssrc32, xout, N, stream);
    }
}